// Round 1
// baseline (55.464 us; speedup 1.0000x reference)
//
#include <hip/hip_runtime.h>

// Algebraic collapse of the quantum circuit:
//   state = prod_w RX_w(x[b,w]) RX_w(thetas[w]) |0...0>  (product state!)
//   RX(a)RX(b) = RX(a+b)  =>  qubit w holds RX(x+theta)|0>
//   <Z_w> = cos^2(phi/2) - sin^2(phi/2) = cos(phi),  phi = x[b,w] + thetas[w]
// Output [B, n_qubits] float32: out[b,w] = cosf(x[b,w] + thetas[w]).

__global__ void rx_expz_kernel(const float* __restrict__ x,
                               const float* __restrict__ thetas,
                               float* __restrict__ out,
                               int total, int n_qubits) {
    int i = blockIdx.x * blockDim.x + threadIdx.x;
    if (i < total) {
        int w = i % n_qubits;          // wire index within the row
        out[i] = cosf(x[i] + thetas[w]);
    }
}

extern "C" void kernel_launch(void* const* d_in, const int* in_sizes, int n_in,
                              void* d_out, int out_size, void* d_ws, size_t ws_size,
                              hipStream_t stream) {
    const float* x      = (const float*)d_in[0];   // [B, n_qubits] f32
    const float* thetas = (const float*)d_in[1];   // [n_qubits]    f32
    // d_in[2] is the python scalar n_qubits (device int) — derive it host-side:
    int n_qubits = in_sizes[1];                    // 20
    int total    = in_sizes[0];                    // B * n_qubits = 640
    float* out   = (float*)d_out;

    int block = 256;
    int grid  = (total + block - 1) / block;
    rx_expz_kernel<<<grid, block, 0, stream>>>(x, thetas, out, total, n_qubits);
}